// Round 1
// baseline (279.175 us; speedup 1.0000x reference)
//
#include <hip/hip_runtime.h>

typedef unsigned short u16;
typedef __bf16 bf16x8 __attribute__((ext_vector_type(8)));
typedef float f32x4 __attribute__((ext_vector_type(4)));

// Problem constants (from reference)
#define NB 16      // batches
#define NC 64      // channels
#define NK 207     // nodes (K_DIM)
#define NL 64      // time (L_DIM)
#define KP 224     // padded GEMM K-dim over nodes (207 -> 224 = 7*32)
#define NKL 13248  // NK*NL
#define NROWP 13312 // padded (j,l) rows = 52*256
#define GROWS 1152 // stacked-G rows: 5*208 + 112 pad
#define CIN 320

__device__ __forceinline__ u16 f2bf(float f) {
  unsigned u = __builtin_bit_cast(unsigned, f);
  u += 0x7FFFu + ((u >> 16) & 1u);   // RNE; inputs are never NaN
  return (u16)(u >> 16);
}

// ---------------- prep: x (B,C,K*L) fp32 -> xT[b][l][c][k0..223] bf16 -------
__global__ void k_prep_x(const float* __restrict__ x, u16* __restrict__ xT) {
  // grid (7 ktile, 64 c, 16 b), 256 threads
  int kt = blockIdx.x, c = blockIdx.y, b = blockIdx.z;
  __shared__ float lds[32][65];
  int t = threadIdx.x;
  int l = t & 63, r0 = t >> 6;
  const float* xp = x + (size_t)(b * 64 + c) * NKL;
  for (int r = r0; r < 32; r += 4) {
    int k = kt * 32 + r;
    lds[r][l] = (k < NK) ? xp[k * 64 + l] : 0.f;
  }
  __syncthreads();
  int kk = t & 31, lq = t >> 5;
  for (int l2 = lq; l2 < 64; l2 += 8) {
    xT[((size_t)b * 4096 + l2 * 64 + c) * KP + kt * 32 + kk] = f2bf(lds[kk][l2]);
  }
}

// ---- prep: A -> Abf (row-major), AbfT (transposed), G blocks q=1,3 (plain A)
__global__ void k_prep_A(const float* __restrict__ a0, const float* __restrict__ a1,
                         u16* __restrict__ Abf, u16* __restrict__ AbfT,
                         u16* __restrict__ G) {
  // grid (8 rowtile, 2 w, 16 b), 256 threads
  int rt = blockIdx.x, w = blockIdx.y, b = blockIdx.z;
  const float* A = (w ? a1 : a0) + (size_t)b * NK * NK;
  __shared__ float lds[32][225];
  int t = threadIdx.x;
  int m0 = rt * 32;
  for (int idx = t; idx < 32 * KP; idx += 256) {
    int r = idx / KP, k = idx - r * KP;
    int m = m0 + r;
    float v = (m < NK && k < NK) ? A[m * NK + k] : 0.f;
    lds[r][k] = v;
    u16 bf = f2bf(v);
    Abf[(((size_t)b * 2 + w) * 256 + m) * KP + k] = bf;
    if (m < 208) G[((size_t)b * GROWS + (1 + 2 * w) * 208 + m) * KP + k] = bf;
  }
  __syncthreads();
  if (rt < 7) {
    for (int idx = t; idx < KP * 32; idx += 256) {
      int k = idx >> 5, mm = idx & 31;
      AbfT[(((size_t)b * 2 + w) * 256 + k) * KP + m0 + mm] = f2bf(lds[mm][k]);
    }
  }
}

// ---- prep: identity block, zero pads, W->bf16 -------------------------------
__global__ void k_prep_I(const float* __restrict__ W, u16* __restrict__ G,
                         u16* __restrict__ AbfT, u16* __restrict__ Wbf) {
  // grid (416, 16)
  int b = blockIdx.y;
  int idx = blockIdx.x * 256 + threadIdx.x;
  if (idx < 46592) {                       // G block q=0: identity, rows 0..207
    int j = idx / KP, k = idx - j * KP;
    G[((size_t)b * GROWS + j) * KP + k] = (j == k && j < NK) ? (u16)0x3F80 : (u16)0;
  } else if (idx < 71680) {                // G rows 1040..1151 -> 0
    int r = idx - 46592;
    G[(size_t)b * GROWS * KP + 1040 * KP + r] = 0;
  } else if (idx < 86016) {                // AbfT rows 224..255 -> 0 (both w)
    int r = idx - 71680;
    int w = r / 7168, rr = r - w * 7168;
    AbfT[(((size_t)b * 2 + w) * 256 + 224) * KP + rr] = 0;
  } else if (b == 0) {                     // W convert (once)
    int r = idx - 86016;
    if (r < 64 * CIN) Wbf[r] = f2bf(W[r]);
  }
}

// ---- prep: A^2 via MFMA -> G blocks q=2,4 ----------------------------------
__global__ void k_asq(const u16* __restrict__ Abf, const u16* __restrict__ AbfT,
                      u16* __restrict__ G) {
  // grid (4 ntile, 4 mtile, 32=b*2+w), 256 threads, waves 2x2, wave tile 32x32
  int b = blockIdx.z >> 1, w = blockIdx.z & 1;
  int lane = threadIdx.x & 63, wave = threadIdx.x >> 6;
  int wm = wave >> 1, wn = wave & 1;
  const u16* Ab = Abf + ((size_t)b * 2 + w) * 256 * KP;
  const u16* At = AbfT + ((size_t)b * 2 + w) * 256 * KP;
  int m0 = blockIdx.y * 64 + wm * 32;
  int n0 = blockIdx.x * 64 + wn * 32;
  int r = lane & 15, q = lane >> 4;
  f32x4 acc[2][2] = {};
  for (int k0 = 0; k0 < KP; k0 += 32) {
    bf16x8 af[2], bg[2];
    for (int i = 0; i < 2; i++)
      af[i] = *(const bf16x8*)(Ab + (size_t)(m0 + i * 16 + r) * KP + k0 + q * 8);
    for (int i = 0; i < 2; i++)
      bg[i] = *(const bf16x8*)(At + (size_t)(n0 + i * 16 + r) * KP + k0 + q * 8);
    for (int i = 0; i < 2; i++)
      for (int j = 0; j < 2; j++)
        acc[i][j] = __builtin_amdgcn_mfma_f32_16x16x32_bf16(af[i], bg[j], acc[i][j], 0, 0, 0);
  }
  int qblk = 2 + 2 * w;
  for (int i = 0; i < 2; i++)
    for (int j = 0; j < 2; j++)
      for (int rr = 0; rr < 4; rr++) {
        int mj = m0 + i * 16 + q * 4 + rr;
        int nk = n0 + j * 16 + r;
        if (mj < 208 && nk < KP)
          G[((size_t)b * GROWS + qblk * 208 + mj) * KP + nk] = f2bf(acc[i][j][rr]);
      }
}

// ---- K1: H[(j,l)][(p,c)] = Gstack(1040x224) @ xT(4096x224)^T ---------------
__global__ __launch_bounds__(256) void k_diffuse(const u16* __restrict__ G,
                                                 const u16* __restrict__ xT,
                                                 u16* __restrict__ H, int b0) {
  // grid (32 ntile, 9 mtile, nc), 256 threads, waves 2x2, wave tile 64x64
  int bl = blockIdx.z;
  int b = b0 + bl;
  int lane = threadIdx.x & 63, wave = threadIdx.x >> 6;
  int wm = wave >> 1, wn = wave & 1;
  int m_wg = blockIdx.y * 128, n_wg = blockIdx.x * 128;
  const u16* Gb = G + (size_t)b * GROWS * KP;
  const u16* Xb = xT + (size_t)b * 4096 * KP;
  __shared__ __align__(16) u16 lds[16 * 512];  // 16 frag-tiles, 1KB each
  int r = lane & 15, q = lane >> 4;
  f32x4 acc[4][4] = {};
  for (int k0 = 0; k0 < KP; k0 += 32) {
    for (int i = 0; i < 4; i++) {  // each wave stages 4 of 16 tiles
      int t = wave * 4 + i;
      const u16* src = (t < 8)
          ? Gb + (size_t)(m_wg + t * 16 + r) * KP + k0 + q * 8
          : Xb + (size_t)(n_wg + (t - 8) * 16 + r) * KP + k0 + q * 8;
      *(int4*)(&lds[t * 512 + lane * 8]) = *(const int4*)src;
    }
    __syncthreads();
    bf16x8 af[4], bg[4];
    for (int i = 0; i < 4; i++) af[i] = *(const bf16x8*)(&lds[(wm * 4 + i) * 512 + lane * 8]);
    for (int i = 0; i < 4; i++) bg[i] = *(const bf16x8*)(&lds[(8 + wn * 4 + i) * 512 + lane * 8]);
    for (int i = 0; i < 4; i++)
      for (int j = 0; j < 4; j++)
        acc[i][j] = __builtin_amdgcn_mfma_f32_16x16x32_bf16(af[i], bg[j], acc[i][j], 0, 0, 0);
    __syncthreads();
  }
  u16* Hb = H + (size_t)bl * NROWP * CIN;
  for (int i = 0; i < 4; i++)
    for (int rr = 0; rr < 4; rr++) {
      int m = m_wg + (wm * 4 + i) * 16 + q * 4 + rr;
      int qb = m / 208;
      int j = m - qb * 208;
      if (qb < 5 && j < NK) {
        for (int jj = 0; jj < 4; jj++) {
          int n = n_wg + (wn * 4 + jj) * 16 + r;
          int l = n >> 6, c = n & 63;
          Hb[(size_t)(j * 64 + l) * CIN + qb * 64 + c] = f2bf(acc[i][jj][rr]);
        }
      }
    }
}

// ---- K2: y = Wbf(64x320) @ H(13312x320)^T + bias ---------------------------
__global__ __launch_bounds__(256) void k_conv(const u16* __restrict__ Wbf,
                                              const u16* __restrict__ H,
                                              const float* __restrict__ bias,
                                              float* __restrict__ y, int b0) {
  // grid (52, 1, nc), 256 threads; WG tile 64x256; wave tile 64x64
  int bl = blockIdx.z, b = b0 + bl;
  int lane = threadIdx.x & 63, wave = threadIdx.x >> 6;
  int n_wgbase = blockIdx.x * 256;
  const u16* Hb = H + (size_t)bl * NROWP * CIN;
  __shared__ __align__(16) u16 lds[20 * 512];  // A tiles 0..3, B tiles 4..19
  int r = lane & 15, q = lane >> 4;
  f32x4 acc[4][4] = {};
  for (int k0 = 0; k0 < CIN; k0 += 32) {
    {
      const u16* src = Wbf + (size_t)(wave * 16 + r) * CIN + k0 + q * 8;
      *(int4*)(&lds[wave * 512 + lane * 8]) = *(const int4*)src;
    }
    for (int i = 0; i < 4; i++) {
      int nt = wave * 4 + i;
      const u16* src = Hb + (size_t)(n_wgbase + nt * 16 + r) * CIN + k0 + q * 8;
      *(int4*)(&lds[(4 + nt) * 512 + lane * 8]) = *(const int4*)src;
    }
    __syncthreads();
    bf16x8 af[4], bg[4];
    for (int i = 0; i < 4; i++) af[i] = *(const bf16x8*)(&lds[i * 512 + lane * 8]);
    for (int i = 0; i < 4; i++) bg[i] = *(const bf16x8*)(&lds[(4 + wave * 4 + i) * 512 + lane * 8]);
    for (int i = 0; i < 4; i++)
      for (int j = 0; j < 4; j++)
        acc[i][j] = __builtin_amdgcn_mfma_f32_16x16x32_bf16(af[i], bg[j], acc[i][j], 0, 0, 0);
    __syncthreads();
  }
  float* yb = y + (size_t)b * 64 * NKL;
  for (int i = 0; i < 4; i++)
    for (int rr = 0; rr < 4; rr++) {
      int o = i * 16 + q * 4 + rr;
      float bv = bias[o];
      for (int j = 0; j < 4; j++) {
        int n = n_wgbase + wave * 64 + j * 16 + r;
        if (n < NKL) yb[(size_t)o * NKL + n] = acc[i][j][rr] + bv;
      }
    }
}

extern "C" void kernel_launch(void* const* d_in, const int* in_sizes, int n_in,
                              void* d_out, int out_size, void* d_ws, size_t ws_size,
                              hipStream_t stream) {
  const float* x = (const float*)d_in[0];
  const float* a0 = (const float*)d_in[1];
  const float* a1 = (const float*)d_in[2];
  const float* W = (const float*)d_in[3];
  const float* bias = (const float*)d_in[4];
  float* y = (float*)d_out;
  char* ws = (char*)d_ws;

  size_t off = 0;
  auto alloc = [&](size_t bytes) {
    size_t o = off;
    off = (off + bytes + 511) & ~(size_t)511;
    return o;
  };
  size_t o_xT  = alloc((size_t)NB * 4096 * KP * 2);
  size_t o_G   = alloc((size_t)NB * GROWS * KP * 2);
  size_t o_Ab  = alloc((size_t)NB * 2 * 256 * KP * 2);
  size_t o_At  = alloc((size_t)NB * 2 * 256 * KP * 2);
  size_t o_Wb  = alloc((size_t)64 * CIN * 2);
  size_t fixed = off;
  size_t per_h = (size_t)NROWP * CIN * 2;

  int nc = 16;
  while (nc > 1 && fixed + (size_t)nc * per_h > ws_size) nc >>= 1;
  size_t o_H = fixed;

  u16* xT  = (u16*)(ws + o_xT);
  u16* G   = (u16*)(ws + o_G);
  u16* Abf = (u16*)(ws + o_Ab);
  u16* AbfT= (u16*)(ws + o_At);
  u16* Wbf = (u16*)(ws + o_Wb);
  u16* H   = (u16*)(ws + o_H);

  k_prep_x<<<dim3(7, 64, 16), 256, 0, stream>>>(x, xT);
  k_prep_A<<<dim3(8, 2, 16), 256, 0, stream>>>(a0, a1, Abf, AbfT, G);
  k_prep_I<<<dim3(416, 16), 256, 0, stream>>>(W, G, AbfT, Wbf);
  k_asq<<<dim3(4, 4, 32), 256, 0, stream>>>(Abf, AbfT, G);
  for (int c0 = 0; c0 < 16; c0 += nc) {
    k_diffuse<<<dim3(32, 9, nc), 256, 0, stream>>>(G, xT, H, c0);
    k_conv<<<dim3(52, 1, nc), 256, 0, stream>>>(Wbf, H, bias, y, c0);
  }
}

// Round 2
// 267.405 us; speedup vs baseline: 1.0440x; 1.0440x over previous
//
#include <hip/hip_runtime.h>

typedef unsigned short u16;
typedef __bf16 bf16x8 __attribute__((ext_vector_type(8)));
typedef float f32x4 __attribute__((ext_vector_type(4)));

// Problem constants (from reference)
#define NB 16      // batches
#define NC 64      // channels
#define NK 207     // nodes (K_DIM)
#define NL 64      // time (L_DIM)
#define KP 224     // padded GEMM K-dim over nodes (207 -> 224 = 7*32)
#define NKL 13248  // NK*NL
#define NROWP 13312 // padded (j,l) rows = 52*256
#define GROWS 1152 // stacked-G rows: 5*208 + 112 pad
#define CIN 320

__device__ __forceinline__ u16 f2bf(float f) {
  unsigned u = __builtin_bit_cast(unsigned, f);
  u += 0x7FFFu + ((u >> 16) & 1u);   // RNE; inputs are never NaN
  return (u16)(u >> 16);
}

// async global->LDS, 16 B per lane. ldst must be (wave-uniform base + lane*16).
__device__ __forceinline__ void g2l16(const u16* gsrc, u16* ldst) {
  __builtin_amdgcn_global_load_lds(
      (const __attribute__((address_space(1))) unsigned int*)gsrc,
      (__attribute__((address_space(3))) unsigned int*)ldst, 16, 0, 0);
}

// ---------------- prep: x (B,C,K*L) fp32 -> xT[b][(l*64+c)][k0..223] bf16 ----
#define XPAD 225   // odd fp32 stride: conflict-free column writes
__global__ __launch_bounds__(256) void k_prep_x(const float* __restrict__ x,
                                                u16* __restrict__ xT) {
  // grid (64 c, 16 b), 256 threads; one (b,c) plane per block
  int c = blockIdx.x, b = blockIdx.y;
  __shared__ float lds[64 * XPAD];
  const float* xp = x + (size_t)(b * 64 + c) * NKL;
  int t = threadIdx.x;
  for (int i = t; i < NKL; i += 256) {        // coalesced fp32 read
    int k = i >> 6, l = i & 63;
    lds[l * XPAD + k] = xp[i];
  }
  __syncthreads();
  for (int ch = t; ch < 64 * 28; ch += 256) { // 28 int4 chunks per l-row
    int l = ch / 28, kc = ch - l * 28;
    u16 v[8] __attribute__((aligned(16)));
    for (int j = 0; j < 8; j++) {
      int k = kc * 8 + j;
      float f = (k < NK) ? lds[l * XPAD + k] : 0.f;
      v[j] = f2bf(f);
    }
    *(int4*)(xT + ((size_t)b * 4096 + (size_t)l * 64 + c) * KP + kc * 8) = *(int4*)v;
  }
}

// ---- prep: A -> Abf (row-major), AbfT (transposed), G blocks q=1,3 (plain A)
__global__ void k_prep_A(const float* __restrict__ a0, const float* __restrict__ a1,
                         u16* __restrict__ Abf, u16* __restrict__ AbfT,
                         u16* __restrict__ G) {
  // grid (8 rowtile, 2 w, 16 b), 256 threads
  int rt = blockIdx.x, w = blockIdx.y, b = blockIdx.z;
  const float* A = (w ? a1 : a0) + (size_t)b * NK * NK;
  __shared__ float lds[32][225];
  int t = threadIdx.x;
  int m0 = rt * 32;
  for (int idx = t; idx < 32 * KP; idx += 256) {
    int r = idx / KP, k = idx - r * KP;
    int m = m0 + r;
    float v = (m < NK && k < NK) ? A[m * NK + k] : 0.f;
    lds[r][k] = v;
    u16 bf = f2bf(v);
    Abf[(((size_t)b * 2 + w) * 256 + m) * KP + k] = bf;
    if (m < 208) G[((size_t)b * GROWS + (1 + 2 * w) * 208 + m) * KP + k] = bf;
  }
  __syncthreads();
  if (rt < 7) {
    for (int idx = t; idx < KP * 32; idx += 256) {
      int k = idx >> 5, mm = idx & 31;
      AbfT[(((size_t)b * 2 + w) * 256 + k) * KP + m0 + mm] = f2bf(lds[mm][k]);
    }
  }
}

// ---- prep: identity block, zero pads, W->bf16 -------------------------------
__global__ void k_prep_I(const float* __restrict__ W, u16* __restrict__ G,
                         u16* __restrict__ AbfT, u16* __restrict__ Wbf) {
  // grid (416, 16)
  int b = blockIdx.y;
  int idx = blockIdx.x * 256 + threadIdx.x;
  if (idx < 46592) {                       // G block q=0: identity, rows 0..207
    int j = idx / KP, k = idx - j * KP;
    G[((size_t)b * GROWS + j) * KP + k] = (j == k && j < NK) ? (u16)0x3F80 : (u16)0;
  } else if (idx < 71680) {                // G rows 1040..1151 -> 0
    int r = idx - 46592;
    G[(size_t)b * GROWS * KP + 1040 * KP + r] = 0;
  } else if (idx < 86016) {                // AbfT rows 224..255 -> 0 (both w)
    int r = idx - 71680;
    int w = r / 7168, rr = r - w * 7168;
    AbfT[(((size_t)b * 2 + w) * 256 + 224) * KP + rr] = 0;
  } else if (b == 0) {                     // W convert (once)
    int r = idx - 86016;
    if (r < 64 * CIN) Wbf[r] = f2bf(W[r]);
  }
}

// ---- prep: A^2 via MFMA -> G blocks q=2,4 ----------------------------------
__global__ void k_asq(const u16* __restrict__ Abf, const u16* __restrict__ AbfT,
                      u16* __restrict__ G) {
  // grid (4 ntile, 4 mtile, 32=b*2+w), 256 threads, waves 2x2, wave tile 32x32
  int b = blockIdx.z >> 1, w = blockIdx.z & 1;
  int lane = threadIdx.x & 63, wave = threadIdx.x >> 6;
  int wm = wave >> 1, wn = wave & 1;
  const u16* Ab = Abf + ((size_t)b * 2 + w) * 256 * KP;
  const u16* At = AbfT + ((size_t)b * 2 + w) * 256 * KP;
  int m0 = blockIdx.y * 64 + wm * 32;
  int n0 = blockIdx.x * 64 + wn * 32;
  int r = lane & 15, q = lane >> 4;
  f32x4 acc[2][2] = {};
  for (int k0 = 0; k0 < KP; k0 += 32) {
    bf16x8 af[2], bg[2];
    for (int i = 0; i < 2; i++)
      af[i] = *(const bf16x8*)(Ab + (size_t)(m0 + i * 16 + r) * KP + k0 + q * 8);
    for (int i = 0; i < 2; i++)
      bg[i] = *(const bf16x8*)(At + (size_t)(n0 + i * 16 + r) * KP + k0 + q * 8);
    for (int i = 0; i < 2; i++)
      for (int j = 0; j < 2; j++)
        acc[i][j] = __builtin_amdgcn_mfma_f32_16x16x32_bf16(af[i], bg[j], acc[i][j], 0, 0, 0);
  }
  int qblk = 2 + 2 * w;
  for (int i = 0; i < 2; i++)
    for (int j = 0; j < 2; j++)
      for (int rr = 0; rr < 4; rr++) {
        int mj = m0 + i * 16 + q * 4 + rr;
        int nk = n0 + j * 16 + r;
        if (mj < 208 && nk < KP)
          G[((size_t)b * GROWS + qblk * 208 + mj) * KP + nk] = f2bf(acc[i][j][rr]);
      }
}

// ---- K1: H[(j,l)][(p,c)] = Gstack(1040x224) @ xT(4096x224)^T ---------------
__global__ __launch_bounds__(256) void k_diffuse(const u16* __restrict__ G,
                                                 const u16* __restrict__ xT,
                                                 u16* __restrict__ H, int b0) {
  // grid (32 ntile, 9 mtile, nc), 256 threads, waves 2x2, wave tile 64x64
  int bl = blockIdx.z;
  int b = b0 + bl;
  int lane = threadIdx.x & 63, wave = threadIdx.x >> 6;
  int wm = wave >> 1, wn = wave & 1;
  int m_wg = blockIdx.y * 128, n_wg = blockIdx.x * 128;
  const u16* Gb = G + (size_t)b * GROWS * KP;
  const u16* Xb = xT + (size_t)b * 4096 * KP;
  __shared__ __align__(16) u16 lds[16 * 512];  // 16 frag-tiles, 1KB each
  int r = lane & 15, q = lane >> 4;
  f32x4 acc[4][4] = {};
  // per-wave staging source pointers (4 of the 16 frag-tiles each)
  const u16* src[4];
  u16* dst[4];
  for (int i = 0; i < 4; i++) {
    int t = wave * 4 + i;
    src[i] = (t < 8)
        ? Gb + (size_t)(m_wg + t * 16 + r) * KP + q * 8
        : Xb + (size_t)(n_wg + (t - 8) * 16 + r) * KP + q * 8;
    dst[i] = &lds[t * 512 + lane * 8];   // = wave-uniform base + lane*16B
  }
  for (int k0 = 0; k0 < KP; k0 += 32) {
    for (int i = 0; i < 4; i++) g2l16(src[i] + k0, dst[i]);
    __syncthreads();
    bf16x8 af[4], bg[4];
    for (int i = 0; i < 4; i++) af[i] = *(const bf16x8*)(&lds[(wm * 4 + i) * 512 + lane * 8]);
    for (int i = 0; i < 4; i++) bg[i] = *(const bf16x8*)(&lds[(8 + wn * 4 + i) * 512 + lane * 8]);
    for (int i = 0; i < 4; i++)
      for (int j = 0; j < 4; j++)
        acc[i][j] = __builtin_amdgcn_mfma_f32_16x16x32_bf16(af[i], bg[j], acc[i][j], 0, 0, 0);
    __syncthreads();
  }
  u16* Hb = H + (size_t)bl * NROWP * CIN;
  for (int i = 0; i < 4; i++)
    for (int rr = 0; rr < 4; rr++) {
      int m = m_wg + (wm * 4 + i) * 16 + q * 4 + rr;
      int qb = m / 208;
      int j = m - qb * 208;
      if (qb < 5 && j < NK) {
        for (int jj = 0; jj < 4; jj++) {
          int n = n_wg + (wn * 4 + jj) * 16 + r;
          int l = n >> 6, c = n & 63;
          Hb[(size_t)(j * 64 + l) * CIN + qb * 64 + c] = f2bf(acc[i][jj][rr]);
        }
      }
    }
}

// ---- K2: y = Wbf(64x320) @ H(13312x320)^T + bias ---------------------------
__global__ __launch_bounds__(256) void k_conv(const u16* __restrict__ Wbf,
                                              const u16* __restrict__ H,
                                              const float* __restrict__ bias,
                                              float* __restrict__ y, int b0) {
  // grid (52, 1, nc), 256 threads; WG tile 64x256; wave tile 64x64
  int bl = blockIdx.z, b = b0 + bl;
  int lane = threadIdx.x & 63, wave = threadIdx.x >> 6;
  int n_wgbase = blockIdx.x * 256;
  const u16* Hb = H + (size_t)bl * NROWP * CIN;
  __shared__ __align__(16) u16 lds[20 * 512];  // A tiles 0..3, B tiles 4..19
  int r = lane & 15, q = lane >> 4;
  f32x4 acc[4][4] = {};
  const u16* asrc = Wbf + (size_t)(wave * 16 + r) * CIN + q * 8;
  u16* adst = &lds[wave * 512 + lane * 8];
  const u16* bsrc[4];
  u16* bdst[4];
  for (int i = 0; i < 4; i++) {
    int nt = wave * 4 + i;
    bsrc[i] = Hb + (size_t)(n_wgbase + nt * 16 + r) * CIN + q * 8;
    bdst[i] = &lds[(4 + nt) * 512 + lane * 8];
  }
  for (int k0 = 0; k0 < CIN; k0 += 32) {
    g2l16(asrc + k0, adst);
    for (int i = 0; i < 4; i++) g2l16(bsrc[i] + k0, bdst[i]);
    __syncthreads();
    bf16x8 af[4], bg[4];
    for (int i = 0; i < 4; i++) af[i] = *(const bf16x8*)(&lds[i * 512 + lane * 8]);
    for (int i = 0; i < 4; i++) bg[i] = *(const bf16x8*)(&lds[(4 + wave * 4 + i) * 512 + lane * 8]);
    for (int i = 0; i < 4; i++)
      for (int j = 0; j < 4; j++)
        acc[i][j] = __builtin_amdgcn_mfma_f32_16x16x32_bf16(af[i], bg[j], acc[i][j], 0, 0, 0);
    __syncthreads();
  }
  float* yb = y + (size_t)b * 64 * NKL;
  for (int i = 0; i < 4; i++)
    for (int rr = 0; rr < 4; rr++) {
      int o = i * 16 + q * 4 + rr;
      float bv = bias[o];
      for (int j = 0; j < 4; j++) {
        int n = n_wgbase + wave * 64 + j * 16 + r;
        if (n < NKL) yb[(size_t)o * NKL + n] = acc[i][j][rr] + bv;
      }
    }
}

extern "C" void kernel_launch(void* const* d_in, const int* in_sizes, int n_in,
                              void* d_out, int out_size, void* d_ws, size_t ws_size,
                              hipStream_t stream) {
  const float* x = (const float*)d_in[0];
  const float* a0 = (const float*)d_in[1];
  const float* a1 = (const float*)d_in[2];
  const float* W = (const float*)d_in[3];
  const float* bias = (const float*)d_in[4];
  float* y = (float*)d_out;
  char* ws = (char*)d_ws;

  size_t off = 0;
  auto alloc = [&](size_t bytes) {
    size_t o = off;
    off = (off + bytes + 511) & ~(size_t)511;
    return o;
  };
  size_t o_xT  = alloc((size_t)NB * 4096 * KP * 2);
  size_t o_G   = alloc((size_t)NB * GROWS * KP * 2);
  size_t o_Ab  = alloc((size_t)NB * 2 * 256 * KP * 2);
  size_t o_At  = alloc((size_t)NB * 2 * 256 * KP * 2);
  size_t o_Wb  = alloc((size_t)64 * CIN * 2);
  size_t fixed = off;
  size_t per_h = (size_t)NROWP * CIN * 2;

  int nc = 16;
  while (nc > 1 && fixed + (size_t)nc * per_h > ws_size) nc >>= 1;
  size_t o_H = fixed;

  u16* xT  = (u16*)(ws + o_xT);
  u16* G   = (u16*)(ws + o_G);
  u16* Abf = (u16*)(ws + o_Ab);
  u16* AbfT= (u16*)(ws + o_At);
  u16* Wbf = (u16*)(ws + o_Wb);
  u16* H   = (u16*)(ws + o_H);

  k_prep_x<<<dim3(64, 16), 256, 0, stream>>>(x, xT);
  k_prep_A<<<dim3(8, 2, 16), 256, 0, stream>>>(a0, a1, Abf, AbfT, G);
  k_prep_I<<<dim3(416, 16), 256, 0, stream>>>(W, G, AbfT, Wbf);
  k_asq<<<dim3(4, 4, 32), 256, 0, stream>>>(Abf, AbfT, G);
  for (int c0 = 0; c0 < 16; c0 += nc) {
    k_diffuse<<<dim3(32, 9, nc), 256, 0, stream>>>(G, xT, H, c0);
    k_conv<<<dim3(52, 1, nc), 256, 0, stream>>>(Wbf, H, bias, y, c0);
  }
}